// Round 4
// baseline (151.643 us; speedup 1.0000x reference)
//
#include <hip/hip_runtime.h>

// Problem constants (reference: NUM_SAMPLES=8192, EMBED=64, TAU=0.2)
#define EMBED        64
#define NS           8192
#define NTILE        256            // 32-row tiles per matrix
#define JCHUNKS      8
#define JT_PER_CHUNK 32             // NTILE / JCHUNKS
#define C_L2E_TAU    7.21347520444482f   // INV_TAU * log2(e) = 5 / ln(2)

typedef _Float16 half8  __attribute__((ext_vector_type(8)));
typedef float    f32x16 __attribute__((ext_vector_type(16)));

// async global->LDS, 16B/lane. Global addr is per-lane; LDS base wave-uniform.
#define GLDS16(g, l) __builtin_amdgcn_global_load_lds( \
    (const __attribute__((address_space(1))) void*)(g), \
    (__attribute__((address_space(3))) void*)(l), 16, 0, 0)

// ---------------------------------------------------------------------------
// Prep: gather + f32->(h,l) fp16 split + diag, writing fragment-major layout
//   Efrag[mat][tile(256)][frag(8)][lane(64)][8 f16],  frag = hl*4 + ktile
// MFMA 32x32x16 fragment: lane l, elem j -> row = l&31, k = kt*16+(l>>5)*8+j
// Block = one (mat,tile); wave = one ktile; thread reads 32B of its row.
// ---------------------------------------------------------------------------
__global__ __launch_bounds__(256) void prep_kernel(
    const float* __restrict__ users, const float* __restrict__ items,
    const int* __restrict__ uidx, const int* __restrict__ iidx,
    _Float16* __restrict__ Efrag, float* __restrict__ diag) {
  int b = blockIdx.x;
  int mat = b >> 8, tile = b & 255;
  int kt = threadIdx.x >> 6;              // wave index = k-tile
  int lane = threadIdx.x & 63;
  int r = lane & 31;                      // row within tile
  int k0 = kt * 16 + (lane >> 5) * 8;     // my 8-float slice
  int row = tile * 32 + r;
  int src = mat ? iidx[row] : uidx[row];
  const float4* basep =
      (const float4*)((mat ? items : users) + (size_t)src * EMBED + k0);
  float4 v0 = basep[0], v1 = basep[1];
  float vs[8] = {v0.x, v0.y, v0.z, v0.w, v1.x, v1.y, v1.z, v1.w};

  half8 hh, ll;
  float p = 0.f;
  #pragma unroll
  for (int j = 0; j < 8; ++j) {
    float v = vs[j];
    _Float16 h = (_Float16)v;
    hh[j] = h;
    ll[j] = (_Float16)(v - (float)h);
    p = fmaf(v, v, p);
  }
  _Float16* tb = Efrag + (size_t)(mat * NTILE + tile) * 4096;  // 8KB per tile
  *(half8*)(tb + ((kt)     * 64 + lane) * 8) = hh;   // frag kt     (high)
  *(half8*)(tb + ((4 + kt) * 64 + lane) * 8) = ll;   // frag 4+kt   (low)

  // diag = ||row||^2 : lanes l and l^32 hold the two 8-slices of ktile kt
  p += __shfl_xor(p, 32);
  __shared__ float ds[4][32];
  if (lane < 32) ds[kt][lane] = p;
  __syncthreads();
  if (threadIdx.x < 32)
    diag[mat * NS + tile * 32 + threadIdx.x] =
        ds[0][threadIdx.x] + ds[1][threadIdx.x] +
        ds[2][threadIdx.x] + ds[3][threadIdx.x];
}

// ---------------------------------------------------------------------------
// Main: r = E E^T via split MFMA (hh + hl + lh), fixed-shift exp2, row
// partials. Wave = 32-row strip, block = 4 waves, grid = 2*64*8 = 1024.
// R2-PROVEN schedule: double-buffered LDS, stage-1-ahead, one barrier per jt.
// Epilogue folded: rs += exp2(fma(acc, C, -dv*C))  (2 VALU + 1 trans / elem)
// ---------------------------------------------------------------------------
__global__ __launch_bounds__(256) void ssm_mfma_kernel(
    const _Float16* __restrict__ Efrag, const float* __restrict__ diag,
    float* __restrict__ rowpart) {
  int b = blockIdx.x;
  int jc  = b & (JCHUNKS - 1);
  int rb  = (b >> 3) & 63;
  int mat = b >> 9;
  int wave = threadIdx.x >> 6;
  int lane = threadIdx.x & 63;
  int hf   = lane >> 5;

  int rowtile = rb * 4 + wave;
  int rowbase = rowtile * 32;
  const _Float16* Em = Efrag + (size_t)mat * NTILE * 4096;

  // A fragments (my 32-row strip): frags 0..3 = h ktiles, 4..7 = l ktiles
  half8 a[8];
  #pragma unroll
  for (int f = 0; f < 8; ++f)
    a[f] = *(const half8*)(Em + (size_t)rowtile * 4096 + (f * 64 + lane) * 8);

  // negdvC = -diag * C for the fma-folded epilogue
  // (C/D accumulator slot r -> local row (r&3) + 8*(r>>2) + 4*hf)
  float negdvC[16];
  #pragma unroll
  for (int r = 0; r < 16; ++r)
    negdvC[r] = -diag[mat * NS + rowbase + (r & 3) + 8 * (r >> 2) + 4 * hf]
                * C_L2E_TAU;

  float rs[16];
  #pragma unroll
  for (int r = 0; r < 16; ++r) rs[r] = 0.f;

  __shared__ __align__(16) _Float16 Bbuf[2][4096];   // 2 x 8KB double buffer

  int jt0 = jc * JT_PER_CHUNK;
  auto stage = [&](int buf, int jt) {
    const char* src = (const char*)(Em + (size_t)(jt0 + jt) * 4096) + wave * 2048;
    char* dst = (char*)&Bbuf[buf][0] + wave * 2048;
    GLDS16(src + lane * 16, dst);
    GLDS16(src + 1024 + lane * 16, dst + 1024);
  };

  stage(0, 0);
  __syncthreads();   // drains vmcnt before first use

  for (int jt = 0; jt < JT_PER_CHUNK; ++jt) {
    int cur = jt & 1;
    if (jt + 1 < JT_PER_CHUNK) stage(cur ^ 1, jt + 1);

    half8 bh[4], bl[4];
    #pragma unroll
    for (int k = 0; k < 4; ++k) {
      bh[k] = *(const half8*)(&Bbuf[cur][0] + ((k)     * 64 + lane) * 8);
      bl[k] = *(const half8*)(&Bbuf[cur][0] + ((4 + k) * 64 + lane) * 8);
    }

    f32x16 acc = {0.f,0.f,0.f,0.f,0.f,0.f,0.f,0.f,
                  0.f,0.f,0.f,0.f,0.f,0.f,0.f,0.f};
    __builtin_amdgcn_s_setprio(1);
    #pragma unroll
    for (int k = 0; k < 4; ++k)
      acc = __builtin_amdgcn_mfma_f32_32x32x16_f16(a[k], bh[k], acc, 0, 0, 0);
    #pragma unroll
    for (int k = 0; k < 4; ++k)
      acc = __builtin_amdgcn_mfma_f32_32x32x16_f16(a[k], bl[k], acc, 0, 0, 0);
    #pragma unroll
    for (int k = 0; k < 4; ++k)
      acc = __builtin_amdgcn_mfma_f32_32x32x16_f16(a[4 + k], bh[k], acc, 0, 0, 0);
    __builtin_amdgcn_s_setprio(0);

    // folded epilogue: exp2(acc*C - dv*C), 2 VALU + 1 trans per element
    #pragma unroll
    for (int r = 0; r < 16; ++r)
      rs[r] += __builtin_exp2f(fmaf(acc[r], C_L2E_TAU, negdvC[r]));

    __syncthreads();   // vmcnt(0)+lgkmcnt(0): next buffer staged, reads done
  }

  // reduce row partials across the 32 lanes of each half, store per chunk
  #pragma unroll
  for (int r = 0; r < 16; ++r) {
    float v = rs[r];
    v += __shfl_xor(v, 16);
    v += __shfl_xor(v, 8);
    v += __shfl_xor(v, 4);
    v += __shfl_xor(v, 2);
    v += __shfl_xor(v, 1);
    if ((lane & 31) == 0)
      rowpart[jc * (2 * NS) + mat * NS + rowbase +
              (r & 3) + 8 * (r >> 2) + 4 * hf] = v;
  }
}

// ---------------------------------------------------------------------------
// Finalize stage 1: 64 blocks x 256 rows. Per-row chunk-sum + log, block sum.
// ---------------------------------------------------------------------------
__global__ __launch_bounds__(256) void fin1_kernel(
    const float* __restrict__ rowpart, float* __restrict__ partial) {
  int r = blockIdx.x * 256 + threadIdx.x;     // 0..16383
  float s = 0.f;
  #pragma unroll
  for (int c = 0; c < JCHUNKS; ++c) s += rowpart[c * (2 * NS) + r];
  float l = logf(s);
  #pragma unroll
  for (int off = 32; off; off >>= 1) l += __shfl_down(l, off);
  __shared__ float ps[4];
  if ((threadIdx.x & 63) == 0) ps[threadIdx.x >> 6] = l;
  __syncthreads();
  if (threadIdx.x == 0) partial[blockIdx.x] = ps[0] + ps[1] + ps[2] + ps[3];
}

// ---------------------------------------------------------------------------
// Finalize stage 2: one wave. Blocks 0..31 were users, 32..63 items.
// out[0] = loss_u + loss_i, out[1] = loss_u, out[2] = loss_i
// ---------------------------------------------------------------------------
__global__ __launch_bounds__(64) void fin2_kernel(
    const float* __restrict__ partial, float* __restrict__ out) {
  int t = threadIdx.x;
  float v = partial[t];
  float vu = (t < 32) ? v : 0.f;
  float vi = (t < 32) ? 0.f : v;
  #pragma unroll
  for (int off = 32; off; off >>= 1) {
    vu += __shfl_down(vu, off);
    vi += __shfl_down(vi, off);
  }
  if (t == 0) {
    float su = vu * (1.0f / NS);
    float si = vi * (1.0f / NS);
    out[0] = su + si;
    out[1] = su;
    out[2] = si;
  }
}

// ---------------------------------------------------------------------------
// ws: Efrag 4MB | diag 64KB | rowpart 512KB   (identical footprint to R2)
// partial (64 floats) ALIASES the Efrag region — Efrag is dead once the main
// kernel finishes, and stream order guarantees main -> fin1 -> fin2.
// ---------------------------------------------------------------------------
extern "C" void kernel_launch(void* const* d_in, const int* in_sizes, int n_in,
                              void* d_out, int out_size, void* d_ws, size_t ws_size,
                              hipStream_t stream) {
  const float* users = (const float*)d_in[0];
  const float* items = (const float*)d_in[1];
  const int*   uidx  = (const int*)d_in[2];
  const int*   iidx  = (const int*)d_in[3];
  float* out = (float*)d_out;

  _Float16* Efrag = (_Float16*)d_ws;                         // 2*256*4096 f16 = 4MB
  float* diag     = (float*)((char*)d_ws + (size_t)4194304); // 16384 f32
  float* rowpart  = diag + 2 * NS;                           // 8*16384 f32
  float* partial  = (float*)d_ws;                            // aliases dead Efrag

  prep_kernel<<<2 * NTILE, 256, 0, stream>>>(users, items, uidx, iidx, Efrag, diag);
  ssm_mfma_kernel<<<2 * 64 * JCHUNKS, 256, 0, stream>>>(Efrag, diag, rowpart);
  fin1_kernel<<<64, 256, 0, stream>>>(rowpart, partial);
  fin2_kernel<<<1, 64, 0, stream>>>(partial, out);
}

// Round 5
// 135.620 us; speedup vs baseline: 1.1181x; 1.1181x over previous
//
#include <hip/hip_runtime.h>

// Problem constants (reference: NUM_SAMPLES=8192, EMBED=64, TAU=0.2)
#define EMBED        64
#define NS           8192
#define NTILE        256            // 32-row tiles per matrix
#define JCHUNKS      8
#define JT_PER_CHUNK 32             // NTILE / JCHUNKS
#define C_L2E_TAU    7.21347520444482f   // INV_TAU * log2(e) = 5 / ln(2)

typedef _Float16 half8  __attribute__((ext_vector_type(8)));
typedef float    f32x16 __attribute__((ext_vector_type(16)));

// async global->LDS, 16B/lane. Global addr is per-lane; LDS base wave-uniform.
#define GLDS16(g, l) __builtin_amdgcn_global_load_lds( \
    (const __attribute__((address_space(1))) void*)(g), \
    (__attribute__((address_space(3))) void*)(l), 16, 0, 0)

// Raw v_exp_f32: D = 2^x. Input here is in [-2300, +30]: large negatives
// flush to 0 (desired), no NaN/inf path. Non-volatile: pure, schedulable.
static __device__ __forceinline__ float exp2_raw(float x) {
  float r;
  asm("v_exp_f32 %0, %1" : "=v"(r) : "v"(x));
  return r;
}

// ---------------------------------------------------------------------------
// Prep: gather + f32->(h,l) fp16 split + diag, writing fragment-major layout
//   Efrag[mat][tile(256)][frag(8)][lane(64)][8 f16],  frag = hl*4 + ktile
// MFMA 32x32x16 fragment: lane l, elem j -> row = l&31, k = kt*16+(l>>5)*8+j
// Block = one (mat,tile); wave = one ktile; thread reads 32B of its row.
// (unchanged from R4 — proven)
// ---------------------------------------------------------------------------
__global__ __launch_bounds__(256) void prep_kernel(
    const float* __restrict__ users, const float* __restrict__ items,
    const int* __restrict__ uidx, const int* __restrict__ iidx,
    _Float16* __restrict__ Efrag, float* __restrict__ diag) {
  int b = blockIdx.x;
  int mat = b >> 8, tile = b & 255;
  int kt = threadIdx.x >> 6;              // wave index = k-tile
  int lane = threadIdx.x & 63;
  int r = lane & 31;                      // row within tile
  int k0 = kt * 16 + (lane >> 5) * 8;     // my 8-float slice
  int row = tile * 32 + r;
  int src = mat ? iidx[row] : uidx[row];
  const float4* basep =
      (const float4*)((mat ? items : users) + (size_t)src * EMBED + k0);
  float4 v0 = basep[0], v1 = basep[1];
  float vs[8] = {v0.x, v0.y, v0.z, v0.w, v1.x, v1.y, v1.z, v1.w};

  half8 hh, ll;
  float p = 0.f;
  #pragma unroll
  for (int j = 0; j < 8; ++j) {
    float v = vs[j];
    _Float16 h = (_Float16)v;
    hh[j] = h;
    ll[j] = (_Float16)(v - (float)h);
    p = fmaf(v, v, p);
  }
  _Float16* tb = Efrag + (size_t)(mat * NTILE + tile) * 4096;  // 8KB per tile
  *(half8*)(tb + ((kt)     * 64 + lane) * 8) = hh;   // frag kt     (high)
  *(half8*)(tb + ((4 + kt) * 64 + lane) * 8) = ll;   // frag 4+kt   (low)

  // diag = ||row||^2 : lanes l and l^32 hold the two 8-slices of ktile kt
  p += __shfl_xor(p, 32);
  __shared__ float ds[4][32];
  if (lane < 32) ds[kt][lane] = p;
  __syncthreads();
  if (threadIdx.x < 32)
    diag[mat * NS + tile * 32 + threadIdx.x] =
        ds[0][threadIdx.x] + ds[1][threadIdx.x] +
        ds[2][threadIdx.x] + ds[3][threadIdx.x];
}

// ---------------------------------------------------------------------------
// Main: r = E E^T via split MFMA (hh + hl + lh), fixed-shift exp2, row
// partials. Wave = 32-row strip, block = 4 waves, grid = 2*64*8 = 1024.
// R2-PROVEN schedule: double-buffered LDS, stage-1-ahead, one barrier per jt.
// Epilogue floor: acc INITIALIZED to -diag (subtract folded into MFMA C-in),
// then rs += v_exp_f32(acc * C) — 3 VALU-class ops per element. No setprio.
// ---------------------------------------------------------------------------
__global__ __launch_bounds__(256) void ssm_mfma_kernel(
    const _Float16* __restrict__ Efrag, const float* __restrict__ diag,
    float* __restrict__ rowpart) {
  int b = blockIdx.x;
  int jc  = b & (JCHUNKS - 1);
  int rb  = (b >> 3) & 63;
  int mat = b >> 9;
  int wave = threadIdx.x >> 6;
  int lane = threadIdx.x & 63;
  int hf   = lane >> 5;

  int rowtile = rb * 4 + wave;
  int rowbase = rowtile * 32;
  const _Float16* Em = Efrag + (size_t)mat * NTILE * 4096;

  // A fragments (my 32-row strip): frags 0..3 = h ktiles, 4..7 = l ktiles
  half8 a[8];
  #pragma unroll
  for (int f = 0; f < 8; ++f)
    a[f] = *(const half8*)(Em + (size_t)rowtile * 4096 + (f * 64 + lane) * 8);

  // negdv = -diag for accumulator init
  // (C/D accumulator slot r -> local row (r&3) + 8*(r>>2) + 4*hf)
  float negdv[16];
  #pragma unroll
  for (int r = 0; r < 16; ++r)
    negdv[r] = -diag[mat * NS + rowbase + (r & 3) + 8 * (r >> 2) + 4 * hf];

  float rs[16];
  #pragma unroll
  for (int r = 0; r < 16; ++r) rs[r] = 0.f;

  __shared__ __align__(16) _Float16 Bbuf[2][4096];   // 2 x 8KB double buffer

  int jt0 = jc * JT_PER_CHUNK;
  auto stage = [&](int buf, int jt) {
    const char* src = (const char*)(Em + (size_t)(jt0 + jt) * 4096) + wave * 2048;
    char* dst = (char*)&Bbuf[buf][0] + wave * 2048;
    GLDS16(src + lane * 16, dst);
    GLDS16(src + 1024 + lane * 16, dst + 1024);
  };

  stage(0, 0);
  __syncthreads();   // drains vmcnt before first use

  for (int jt = 0; jt < JT_PER_CHUNK; ++jt) {
    int cur = jt & 1;
    if (jt + 1 < JT_PER_CHUNK) stage(cur ^ 1, jt + 1);

    half8 bh[4], bl[4];
    #pragma unroll
    for (int k = 0; k < 4; ++k) {
      bh[k] = *(const half8*)(&Bbuf[cur][0] + ((k)     * 64 + lane) * 8);
      bl[k] = *(const half8*)(&Bbuf[cur][0] + ((4 + k) * 64 + lane) * 8);
    }

    // acc starts at -d_i: MFMA computes r_ij - d_i directly.
    f32x16 acc;
    #pragma unroll
    for (int r = 0; r < 16; ++r) acc[r] = negdv[r];

    #pragma unroll
    for (int k = 0; k < 4; ++k)
      acc = __builtin_amdgcn_mfma_f32_32x32x16_f16(a[k], bh[k], acc, 0, 0, 0);
    #pragma unroll
    for (int k = 0; k < 4; ++k)
      acc = __builtin_amdgcn_mfma_f32_32x32x16_f16(a[k], bl[k], acc, 0, 0, 0);
    #pragma unroll
    for (int k = 0; k < 4; ++k)
      acc = __builtin_amdgcn_mfma_f32_32x32x16_f16(a[4 + k], bh[k], acc, 0, 0, 0);

    // epilogue: 2^((r_ij - d_i) * 5*log2e)  = exp((r_ij-d_i)/tau)
    #pragma unroll
    for (int r = 0; r < 16; ++r)
      rs[r] += exp2_raw(acc[r] * C_L2E_TAU);

    __syncthreads();   // vmcnt(0)+lgkmcnt(0): next buffer staged, reads done
  }

  // reduce row partials across the 32 lanes of each half, store per chunk
  #pragma unroll
  for (int r = 0; r < 16; ++r) {
    float v = rs[r];
    v += __shfl_xor(v, 16);
    v += __shfl_xor(v, 8);
    v += __shfl_xor(v, 4);
    v += __shfl_xor(v, 2);
    v += __shfl_xor(v, 1);
    if ((lane & 31) == 0)
      rowpart[jc * (2 * NS) + mat * NS + rowbase +
              (r & 3) + 8 * (r >> 2) + 4 * hf] = v;
  }
}

// ---------------------------------------------------------------------------
// Finalize stage 1: 64 blocks x 256 rows. Per-row chunk-sum + log, block sum.
// ---------------------------------------------------------------------------
__global__ __launch_bounds__(256) void fin1_kernel(
    const float* __restrict__ rowpart, float* __restrict__ partial) {
  int r = blockIdx.x * 256 + threadIdx.x;     // 0..16383
  float s = 0.f;
  #pragma unroll
  for (int c = 0; c < JCHUNKS; ++c) s += rowpart[c * (2 * NS) + r];
  float l = logf(s);
  #pragma unroll
  for (int off = 32; off; off >>= 1) l += __shfl_down(l, off);
  __shared__ float ps[4];
  if ((threadIdx.x & 63) == 0) ps[threadIdx.x >> 6] = l;
  __syncthreads();
  if (threadIdx.x == 0) partial[blockIdx.x] = ps[0] + ps[1] + ps[2] + ps[3];
}

// ---------------------------------------------------------------------------
// Finalize stage 2: one wave. Blocks 0..31 were users, 32..63 items.
// out[0] = loss_u + loss_i, out[1] = loss_u, out[2] = loss_i
// ---------------------------------------------------------------------------
__global__ __launch_bounds__(64) void fin2_kernel(
    const float* __restrict__ partial, float* __restrict__ out) {
  int t = threadIdx.x;
  float v = partial[t];
  float vu = (t < 32) ? v : 0.f;
  float vi = (t < 32) ? 0.f : v;
  #pragma unroll
  for (int off = 32; off; off >>= 1) {
    vu += __shfl_down(vu, off);
    vi += __shfl_down(vi, off);
  }
  if (t == 0) {
    float su = vu * (1.0f / NS);
    float si = vi * (1.0f / NS);
    out[0] = su + si;
    out[1] = su;
    out[2] = si;
  }
}

// ---------------------------------------------------------------------------
// ws: Efrag 4MB | diag 64KB | rowpart 512KB   (identical footprint to R2/R4)
// partial (64 floats) ALIASES the Efrag region — Efrag is dead once the main
// kernel finishes, and stream order guarantees main -> fin1 -> fin2.
// ---------------------------------------------------------------------------
extern "C" void kernel_launch(void* const* d_in, const int* in_sizes, int n_in,
                              void* d_out, int out_size, void* d_ws, size_t ws_size,
                              hipStream_t stream) {
  const float* users = (const float*)d_in[0];
  const float* items = (const float*)d_in[1];
  const int*   uidx  = (const int*)d_in[2];
  const int*   iidx  = (const int*)d_in[3];
  float* out = (float*)d_out;

  _Float16* Efrag = (_Float16*)d_ws;                         // 2*256*4096 f16 = 4MB
  float* diag     = (float*)((char*)d_ws + (size_t)4194304); // 16384 f32
  float* rowpart  = diag + 2 * NS;                           // 8*16384 f32
  float* partial  = (float*)d_ws;                            // aliases dead Efrag

  prep_kernel<<<2 * NTILE, 256, 0, stream>>>(users, items, uidx, iidx, Efrag, diag);
  ssm_mfma_kernel<<<2 * 64 * JCHUNKS, 256, 0, stream>>>(Efrag, diag, rowpart);
  fin1_kernel<<<64, 256, 0, stream>>>(rowpart, partial);
  fin2_kernel<<<1, 64, 0, stream>>>(partial, out);
}